// Round 1
// 716.139 us; speedup vs baseline: 2.6967x; 2.6967x over previous
//
#include <hip/hip_runtime.h>
#include <hip/hip_fp16.h>

#define NB 64
#define TT 1024
#define FF 256
#define HH 256
#define GG 768
#define AA 8
#define KP 288          // padded K: 256 (x) + 8 (a) + 24 zeros
#define MM (NB*TT)      // 65536 rows
#define CH 16           // chunks per sequence (cut at reset boundaries)

typedef _Float16 h2v __attribute__((ext_vector_type(2)));
typedef _Float16 v8h __attribute__((ext_vector_type(8)));
typedef float    v4f __attribute__((ext_vector_type(4)));

static __device__ __forceinline__ float fdot2f(unsigned a, unsigned b, float c) {
#if __has_builtin(__builtin_amdgcn_fdot2)
    return __builtin_amdgcn_fdot2(__builtin_bit_cast(h2v, a),
                                  __builtin_bit_cast(h2v, b), c, false);
#else
    h2v av = __builtin_bit_cast(h2v, a), bv = __builtin_bit_cast(h2v, b);
    return c + (float)av.x * (float)bv.x + (float)av.y * (float)bv.y;
#endif
}

static __device__ __forceinline__ unsigned pk_rtn(float a, float b) {
    unsigned lo = (unsigned)__half_as_ushort(__float2half(a));
    unsigned hi = (unsigned)__half_as_ushort(__float2half(b));
    return lo | (hi << 16);
}

// ---------------------------------------------------------------------------
// Kernel 0: robust reset-dtype detection + canonicalization to uint8.
// (unchanged from previous version)
// ---------------------------------------------------------------------------
__global__ __launch_bounds__(1024) void fix_reset(
    const unsigned* __restrict__ src, unsigned char* __restrict__ dst)
{
    __shared__ unsigned red[16];
    const int tid = threadIdx.x;

    unsigned acc = 0;
    #pragma unroll
    for (int i = 0; i < 16; i++)
        acc |= src[tid * 16 + i] & 0xFFFFFF00u;
    #pragma unroll
    for (int off = 32; off >= 1; off >>= 1)
        acc |= __shfl_down(acc, off, 64);
    if ((tid & 63) == 0) red[tid >> 6] = acc;
    __syncthreads();
    unsigned flag = 0;
    #pragma unroll
    for (int i = 0; i < 16; i++) flag |= red[i];
    const bool is_i32 = (flag == 0);

    if (is_i32) {
        const int per = (NB * TT) / 1024;   // 64
        #pragma unroll
        for (int i = 0; i < per; i++) {
            int idx = tid * per + i;
            dst[idx] = (unsigned char)(src[idx] != 0 ? 1 : 0);
        }
    } else {
        unsigned* d4 = (unsigned*)dst;
        #pragma unroll
        for (int i = 0; i < 16; i++)
            d4[tid * 16 + i] = src[tid * 16 + i];
    }
}

// ---------------------------------------------------------------------------
// Kernel 1: build fp16 padded activation matrix xa[MM][KP] = [x | a | 0],
// transposed padded weights wt[GG][KP] = [w_i ; w_a ; 0]^T, and output #3.
// (unchanged)
// ---------------------------------------------------------------------------
__global__ __launch_bounds__(256) void prepass(
    const float* __restrict__ x, const float* __restrict__ a,
    const float* __restrict__ w_i, const float* __restrict__ w_a,
    const float* __restrict__ ihg, float* __restrict__ out3,
    unsigned short* __restrict__ xa, unsigned short* __restrict__ wt)
{
    int idx = blockIdx.x * 256 + threadIdx.x;
    const int E1 = MM * KP;
    const int E2 = GG * KP;
    if (idx < E1) {
        int m = idx / KP, k = idx - m * KP;
        float v = 0.f;
        if (k < FF)            v = x[m * FF + k];
        else if (k < FF + AA)  v = a[m * AA + (k - FF)];
        xa[idx] = __half_as_ushort(__float2half(v));
    } else if (idx < E1 + E2) {
        int j = idx - E1;
        int g = j / KP, k = j - g * KP;
        float v = 0.f;
        if (k < FF)            v = w_i[k * GG + g];
        else if (k < FF + AA)  v = w_a[(k - FF) * GG + g];
        wt[j] = __half_as_ushort(__float2half(v));
    } else if (idx < E1 + E2 + HH) {
        int i = idx - E1 - E2;
        out3[i] = ihg[i];
    }
}

// ---------------------------------------------------------------------------
// Kernel 2: gxa[MM][GG] (fp16) = xa @ W + bias. (unchanged)
// ---------------------------------------------------------------------------
#define LDK 40

__global__ __launch_bounds__(256) void gemm_gxa(
    const unsigned short* __restrict__ xa, const unsigned short* __restrict__ wt,
    const float* __restrict__ bias, unsigned short* __restrict__ gxa)
{
    __shared__ __align__(16) unsigned short As[128 * LDK];
    __shared__ __align__(16) unsigned short Bs[128 * LDK];

    const int bid = blockIdx.x;
    const int gt = bid % 6, mt = bid / 6;
    const int tid = threadIdx.x;
    const int lane = tid & 63, wv = tid >> 6;
    const int srow = tid & 127, shf = tid >> 7;
    const int r15 = lane & 15, q = lane >> 4;

    v4f acc[2][8];
    #pragma unroll
    for (int i = 0; i < 2; i++)
        #pragma unroll
        for (int j = 0; j < 8; j++) acc[i][j] = (v4f){0.f, 0.f, 0.f, 0.f};

    for (int kc = 0; kc < 9; kc++) {
        const uint4* srcA = (const uint4*)(xa + (mt * 128 + srow) * KP + kc * 32 + shf * 16);
        const uint4* srcB = (const uint4*)(wt + (gt * 128 + srow) * KP + kc * 32 + shf * 16);
        uint4 a0 = srcA[0], a1 = srcA[1];
        uint4 b0 = srcB[0], b1 = srcB[1];
        *(uint4*)(As + srow * LDK + shf * 16)     = a0;
        *(uint4*)(As + srow * LDK + shf * 16 + 8) = a1;
        *(uint4*)(Bs + srow * LDK + shf * 16)     = b0;
        *(uint4*)(Bs + srow * LDK + shf * 16 + 8) = b1;
        __syncthreads();

        v8h af[2], bf[8];
        #pragma unroll
        for (int mi = 0; mi < 2; mi++)
            af[mi] = *(const v8h*)(As + (wv * 32 + mi * 16 + r15) * LDK + q * 8);
        #pragma unroll
        for (int nj = 0; nj < 8; nj++)
            bf[nj] = *(const v8h*)(Bs + (nj * 16 + r15) * LDK + q * 8);
        #pragma unroll
        for (int mi = 0; mi < 2; mi++)
            #pragma unroll
            for (int nj = 0; nj < 8; nj++)
                acc[mi][nj] = __builtin_amdgcn_mfma_f32_16x16x32_f16(
                    af[mi], bf[nj], acc[mi][nj], 0, 0, 0);
        __syncthreads();
    }

    #pragma unroll
    for (int mi = 0; mi < 2; mi++) {
        #pragma unroll
        for (int nj = 0; nj < 8; nj++) {
            int col = gt * 128 + nj * 16 + r15;
            float bv = bias[col];
            #pragma unroll
            for (int v = 0; v < 4; v++) {
                int row = mt * 128 + wv * 32 + mi * 16 + q * 4 + v;
                float val = acc[mi][nj][v] + bv;
                gxa[row * GG + col] = __half_as_ushort(__float2half(val));
            }
        }
    }
}

// ---------------------------------------------------------------------------
// Kernel 2.5: pack w_h into the exact per-lane packed-fp16 layout the scan
// wants (whp[wi][lane], wi 0..191 -> coalesced dword loads), and compute
// chunk starts: starts[n][c] = first t >= c*(TT/CH) with reset[n][t]!=0
// (c==0 -> 0; none found -> TT). Chunk c>0 always begins at a reset step,
// so restarting from initial_h is bit-identical to the monolithic scan.
// Runs AFTER gemm_gxa so whp/starts can live in the (now dead) xa region.
// ---------------------------------------------------------------------------
__global__ __launch_bounds__(256) void pack_whp(
    const float* __restrict__ w_h, const unsigned char* __restrict__ rst,
    unsigned* __restrict__ whp, int* __restrict__ starts)
{
    const int bid = blockIdx.x;
    if (bid < 384) {
        int j = bid * 256 + threadIdx.x;       // 0..98303 = 192*512
        int lane = j & 511, wi = j >> 9;
        unsigned val;
        if (wi < 128) {                         // phase-1 weights (zr gates)
            int gi = lane & 255, kh = lane >> 8;
            int g = 2 * gi + ((wi >> 6) & 1);   // wz0 / wz1
            int i = wi & 63;
            int k = kh * 128 + 2 * i;
            val = pk_rtn(w_h[k * GG + g], w_h[(k + 1) * GG + g]);
        } else {                                // phase-2 weights (a gates)
            int g2i = lane & 127, kq = lane >> 7;
            int g = 512 + 2 * g2i + ((wi >> 5) & 1);   // wa0 / wa1
            int i = wi & 31;
            int k = kq * 64 + 2 * i;
            val = pk_rtn(w_h[k * GG + g], w_h[(k + 1) * GG + g]);
        }
        whp[j] = val;
    } else {
        // chunk starts: 64 seqs x 16 chunks, 256 threads loop 4x
        for (int v = threadIdx.x; v < NB * CH; v += 256) {
            int n = v >> 4, c = v & (CH - 1);
            int s;
            if (c == 0) s = 0;
            else {
                s = TT;
                const unsigned char* r = rst + n * TT;
                for (int t = c * (TT / CH); t < TT; t++)
                    if (r[t]) { s = t; break; }
            }
            starts[n * (CH + 1) + c] = s;
            if (c == CH - 1) starts[n * (CH + 1) + CH] = TT;
        }
    }
}

// ---------------------------------------------------------------------------
// Kernel 3: chunked GRU scan. One block (512 thr) per (sequence, chunk).
// Chunk boundaries sit on reset steps, so each chunk independently scans
// from h = initial_h — 1024-way parallelism instead of 64, critical path
// ~66 steps instead of 1024. Per-step math identical to previous version.
// ---------------------------------------------------------------------------
__global__ __launch_bounds__(512) void scan_kernel(
    const unsigned short* __restrict__ gxa, const unsigned* __restrict__ whp,
    const unsigned char* __restrict__ reset, const int* __restrict__ starts,
    const float* __restrict__ ihg, float* __restrict__ out)
{
    __shared__ __align__(16) unsigned int h_pk[128];   // h as packed half2
    __shared__ __align__(16) unsigned int rh_pk[128];  // r*h as packed half2
    __shared__ float2 part_zr[256];
    __shared__ float2 part_a[3][128];
    __shared__ __align__(4) unsigned char rst[TT];

    const int n   = blockIdx.x >> 4;
    const int c   = blockIdx.x & (CH - 1);
    const int tid = threadIdx.x;
    const int kh  = tid >> 8, gi  = tid & 255;   // phase1 role
    const int kq  = tid >> 7, g2i = tid & 127;   // phase2 role

    const int tb = starts[n * (CH + 1) + c];
    const int te = starts[n * (CH + 1) + c + 1];
    if (tb >= te) return;   // empty chunk (uniform exit, before any barrier)

    // stage canonical uint8 reset flags for this sequence
    if (tid < 256)
        ((unsigned int*)rst)[tid] = ((const unsigned int*)(reset + n * TT))[tid];

    // ---- load recurrent weights from packed layout (coalesced dwords) ----
    unsigned wz0[64], wz1[64];
    #pragma unroll
    for (int i = 0; i < 64; i++) wz0[i] = whp[i * 512 + tid];
    #pragma unroll
    for (int i = 0; i < 64; i++) wz1[i] = whp[(64 + i) * 512 + tid];
    unsigned wa0[32], wa1[32];
    #pragma unroll
    for (int i = 0; i < 32; i++) wa0[i] = whp[(128 + i) * 512 + tid];
    #pragma unroll
    for (int i = 0; i < 32; i++) wa1[i] = whp[(160 + i) * 512 + tid];

    // ---- hidden state: lane tid<128 owns h[2*tid], h[2*tid+1] in fp32 ----
    float ih0 = 0.f, ih1 = 0.f, hp0 = 0.f, hp1 = 0.f;
    if (tid < 128) {
        ih0 = ihg[2 * tid]; ih1 = ihg[2 * tid + 1];
        hp0 = ih0; hp1 = ih1;   // correct for c==0; c>0 starts on a reset step
    }
    __syncthreads();  // rst staged

    const unsigned* gxau = (const unsigned*)gxa;
    const int m0 = n * TT;
    unsigned gzr = gxau[(m0 + tb) * 384 + (tid & 255)];
    unsigned gaa = gxau[(m0 + tb) * 384 + 256 + (tid & 127)];

    float zA = 0.f, zB = 0.f, hc0 = 0.f, hc1 = 0.f;

    for (int t = tb; t < te; t++) {
        // apply reset, publish h (packed fp16) for broadcast
        if (tid < 128) {
            bool rb = rst[t] != 0;
            hc0 = rb ? ih0 : hp0;
            hc1 = rb ? ih1 : hp1;
            h_pk[tid] = __builtin_bit_cast(unsigned,
                          __builtin_amdgcn_cvt_pkrtz(hc0, hc1));
        }
        __syncthreads();  // B1

        // prefetch next step's gxa
        int tn = (t + 1 < te) ? t + 1 : t;
        unsigned gzr_n = gxau[(m0 + tn) * 384 + (tid & 255)];
        unsigned gaa_n = gxau[(m0 + tn) * 384 + 256 + (tid & 127)];

        // ---- phase 1: zr partial dots (this lane: 2 gates, 128 k) ----
        float a00 = 0.f, a01 = 0.f, a10 = 0.f, a11 = 0.f;
        const uint4* h4 = (const uint4*)h_pk;
        #pragma unroll
        for (int cc = 0; cc < 16; cc++) {
            uint4 qd = h4[kh * 16 + cc];
            a00 = fdot2f(qd.x, wz0[4*cc+0], a00);
            a01 = fdot2f(qd.y, wz0[4*cc+1], a01);
            a00 = fdot2f(qd.z, wz0[4*cc+2], a00);
            a01 = fdot2f(qd.w, wz0[4*cc+3], a01);
            a10 = fdot2f(qd.x, wz1[4*cc+0], a10);
            a11 = fdot2f(qd.y, wz1[4*cc+1], a11);
            a10 = fdot2f(qd.z, wz1[4*cc+2], a10);
            a11 = fdot2f(qd.w, wz1[4*cc+3], a11);
        }
        float pA = a00 + a01, pB = a10 + a11;
        if (kh) part_zr[gi] = make_float2(pA, pB);
        __syncthreads();  // B2

        if (tid < 256) {  // kh==0 lanes combine + activate
            float2 o = part_zr[gi];
            h2v gz = __builtin_bit_cast(h2v, gzr);
            float vA = pA + o.x + (float)gz.x;
            float vB = pB + o.y + (float)gz.y;
            float sA = 1.f / (1.f + __expf(-vA));
            float sB = 1.f / (1.f + __expf(-vB));
            if (gi < 128) { zA = sA; zB = sB; }
            else {
                int j2 = gi - 128;
                h2v hp = __builtin_bit_cast(h2v, h_pk[j2]);
                float r0 = sA * (float)hp.x, r1 = sB * (float)hp.y;
                rh_pk[j2] = __builtin_bit_cast(unsigned,
                              __builtin_amdgcn_cvt_pkrtz(r0, r1));
            }
        }
        __syncthreads();  // B3

        // ---- phase 2: a-gate partial dots (this lane: 2 gates, 64 k) ----
        float c00 = 0.f, c01 = 0.f, c10 = 0.f, c11 = 0.f;
        const uint4* r4 = (const uint4*)rh_pk;
        #pragma unroll
        for (int cc = 0; cc < 8; cc++) {
            uint4 qd = r4[kq * 8 + cc];
            c00 = fdot2f(qd.x, wa0[4*cc+0], c00);
            c01 = fdot2f(qd.y, wa0[4*cc+1], c01);
            c00 = fdot2f(qd.z, wa0[4*cc+2], c00);
            c01 = fdot2f(qd.w, wa0[4*cc+3], c01);
            c10 = fdot2f(qd.x, wa1[4*cc+0], c10);
            c11 = fdot2f(qd.y, wa1[4*cc+1], c11);
            c10 = fdot2f(qd.z, wa1[4*cc+2], c10);
            c11 = fdot2f(qd.w, wa1[4*cc+3], c11);
        }
        float qA = c00 + c01, qB = c10 + c11;
        if (kq) part_a[kq - 1][g2i] = make_float2(qA, qB);
        __syncthreads();  // B4

        if (tid < 128) {  // combine, tanh, state update, store
            float2 p0 = part_a[0][tid], p1 = part_a[1][tid], p2 = part_a[2][tid];
            h2v ga = __builtin_bit_cast(h2v, gaa);
            float uA = qA + p0.x + p1.x + p2.x + (float)ga.x;
            float uB = qB + p0.y + p1.y + p2.y + (float)ga.y;
            float e2A = __expf(2.f * uA), e2B = __expf(2.f * uB);
            float tA = (e2A - 1.f) / (e2A + 1.f);
            float tB = (e2B - 1.f) / (e2B + 1.f);
            float hn0 = hc0 + zA * (tA - hc0);
            float hn1 = hc1 + zB * (tB - hc1);
            int o = (m0 + t) * HH + 2 * tid;
            *(float2*)(out + o) = make_float2(hn0, hn1);                 // outputs
            *(float2*)(out + MM * HH + o) = make_float2(hn0, hn1);       // states
            hp0 = hn0; hp1 = hn1;
        }
        gzr = gzr_n; gaa = gaa_n;
    }
}

// ---------------------------------------------------------------------------
extern "C" void kernel_launch(void* const* d_in, const int* in_sizes, int n_in,
                              void* d_out, int out_size, void* d_ws, size_t ws_size,
                              hipStream_t stream)
{
    const float* x   = (const float*)d_in[0];
    const float* a   = (const float*)d_in[1];
    const void*  rsv = d_in[2];
    const float* w_i = (const float*)d_in[3];
    const float* w_h = (const float*)d_in[4];
    const float* w_a = (const float*)d_in[5];
    const float* b   = (const float*)d_in[6];
    const float* ih  = (const float*)d_in[7];
    float*       out = (float*)d_out;

    char* ws = (char*)d_ws;
    unsigned short* gxa  = (unsigned short*)ws;                                  // MM*GG fp16 (96 MB)
    unsigned short* xa   = (unsigned short*)(ws + (size_t)MM * GG * 2);          // MM*KP fp16 (37.7 MB)
    unsigned short* wt   = (unsigned short*)(ws + (size_t)MM * GG * 2
                                                + (size_t)MM * KP * 2);          // GG*KP fp16 (0.44 MB)
    unsigned char*  rst8 = (unsigned char*)(ws + (size_t)MM * GG * 2
                                               + (size_t)MM * KP * 2
                                               + (size_t)GG * KP * 2);           // 64 KB canonical resets
    // whp + starts overlap the xa region (dead after gemm_gxa); written by
    // pack_whp which runs after the GEMM. No workspace growth.
    unsigned* whp   = (unsigned*)xa;                                             // 192*512 dwords (384 KB)
    int*      chst  = (int*)(ws + (size_t)MM * GG * 2 + 192 * 512 * 4);          // 64*17 ints

    fix_reset<<<1, 1024, 0, stream>>>((const unsigned*)rsv, rst8);

    int total = MM * KP + GG * KP + HH;
    int pblocks = (total + 255) / 256;
    prepass<<<pblocks, 256, 0, stream>>>(x, a, w_i, w_a, ih,
                                         out + (size_t)2 * MM * HH, xa, wt);
    gemm_gxa<<<512 * 6, 256, 0, stream>>>(xa, wt, b, gxa);
    pack_whp<<<385, 256, 0, stream>>>(w_h, rst8, whp, chst);
    scan_kernel<<<NB * CH, 512, 0, stream>>>(gxa, whp, rst8, chst, ih, out);
}

// Round 2
// 489.268 us; speedup vs baseline: 3.9472x; 1.4637x over previous
//
#include <hip/hip_runtime.h>
#include <hip/hip_fp16.h>

#define NB 64
#define TT 1024
#define FF 256
#define HH 256
#define GG 768
#define AA 8
#define KP 288          // padded K: 256 (x) + 8 (a) + 24 zeros
#define MM (NB*TT)      // 65536 rows
#define SGRP 16         // sequences batched per scan block (MFMA M=16)
#define WCH 16          // time-window per chunk
#define NCH (TT/WCH)    // 64 chunks
#define LDH 264         // LDS row stride (halfs) for h16/rh16: balances banks

typedef _Float16 h2v __attribute__((ext_vector_type(2)));
typedef _Float16 v8h __attribute__((ext_vector_type(8)));
typedef float    v4f __attribute__((ext_vector_type(4)));

static __device__ __forceinline__ unsigned pk_rtn(float a, float b) {
    unsigned lo = (unsigned)__half_as_ushort(__float2half(a));
    unsigned hi = (unsigned)__half_as_ushort(__float2half(b));
    return lo | (hi << 16);
}
static __device__ __forceinline__ float h2f(unsigned short u) {
    return (float)__builtin_bit_cast(_Float16, u);
}
static __device__ __forceinline__ unsigned short f2h(float f) {
    return __half_as_ushort(__float2half(f));
}

// ---------------------------------------------------------------------------
// Kernel 0: robust reset-dtype detection + canonicalization to uint8.
// (unchanged)
// ---------------------------------------------------------------------------
__global__ __launch_bounds__(1024) void fix_reset(
    const unsigned* __restrict__ src, unsigned char* __restrict__ dst)
{
    __shared__ unsigned red[16];
    const int tid = threadIdx.x;

    unsigned acc = 0;
    #pragma unroll
    for (int i = 0; i < 16; i++)
        acc |= src[tid * 16 + i] & 0xFFFFFF00u;
    #pragma unroll
    for (int off = 32; off >= 1; off >>= 1)
        acc |= __shfl_down(acc, off, 64);
    if ((tid & 63) == 0) red[tid >> 6] = acc;
    __syncthreads();
    unsigned flag = 0;
    #pragma unroll
    for (int i = 0; i < 16; i++) flag |= red[i];
    const bool is_i32 = (flag == 0);

    if (is_i32) {
        const int per = (NB * TT) / 1024;   // 64
        #pragma unroll
        for (int i = 0; i < per; i++) {
            int idx = tid * per + i;
            dst[idx] = (unsigned char)(src[idx] != 0 ? 1 : 0);
        }
    } else {
        unsigned* d4 = (unsigned*)dst;
        #pragma unroll
        for (int i = 0; i < 16; i++)
            d4[tid * 16 + i] = src[tid * 16 + i];
    }
}

// ---------------------------------------------------------------------------
// Kernel 1: build fp16 padded activation matrix xa[MM][KP] = [x | a | 0],
// transposed padded weights wt[GG][KP], and output #3. (unchanged)
// ---------------------------------------------------------------------------
__global__ __launch_bounds__(256) void prepass(
    const float* __restrict__ x, const float* __restrict__ a,
    const float* __restrict__ w_i, const float* __restrict__ w_a,
    const float* __restrict__ ihg, float* __restrict__ out3,
    unsigned short* __restrict__ xa, unsigned short* __restrict__ wt)
{
    int idx = blockIdx.x * 256 + threadIdx.x;
    const int E1 = MM * KP;
    const int E2 = GG * KP;
    if (idx < E1) {
        int m = idx / KP, k = idx - m * KP;
        float v = 0.f;
        if (k < FF)            v = x[m * FF + k];
        else if (k < FF + AA)  v = a[m * AA + (k - FF)];
        xa[idx] = f2h(v);
    } else if (idx < E1 + E2) {
        int j = idx - E1;
        int g = j / KP, k = j - g * KP;
        float v = 0.f;
        if (k < FF)            v = w_i[k * GG + g];
        else if (k < FF + AA)  v = w_a[(k - FF) * GG + g];
        wt[j] = f2h(v);
    } else if (idx < E1 + E2 + HH) {
        int i = idx - E1 - E2;
        out3[i] = ihg[i];
    }
}

// ---------------------------------------------------------------------------
// Kernel 2: gxa[MM][GG] (fp16) = xa @ W + bias. (unchanged)
// ---------------------------------------------------------------------------
#define LDK 40

__global__ __launch_bounds__(256) void gemm_gxa(
    const unsigned short* __restrict__ xa, const unsigned short* __restrict__ wt,
    const float* __restrict__ bias, unsigned short* __restrict__ gxa)
{
    __shared__ __align__(16) unsigned short As[128 * LDK];
    __shared__ __align__(16) unsigned short Bs[128 * LDK];

    const int bid = blockIdx.x;
    const int gt = bid % 6, mt = bid / 6;
    const int tid = threadIdx.x;
    const int lane = tid & 63, wv = tid >> 6;
    const int srow = tid & 127, shf = tid >> 7;
    const int r15 = lane & 15, q = lane >> 4;

    v4f acc[2][8];
    #pragma unroll
    for (int i = 0; i < 2; i++)
        #pragma unroll
        for (int j = 0; j < 8; j++) acc[i][j] = (v4f){0.f, 0.f, 0.f, 0.f};

    for (int kc = 0; kc < 9; kc++) {
        const uint4* srcA = (const uint4*)(xa + (mt * 128 + srow) * KP + kc * 32 + shf * 16);
        const uint4* srcB = (const uint4*)(wt + (gt * 128 + srow) * KP + kc * 32 + shf * 16);
        uint4 a0 = srcA[0], a1 = srcA[1];
        uint4 b0 = srcB[0], b1 = srcB[1];
        *(uint4*)(As + srow * LDK + shf * 16)     = a0;
        *(uint4*)(As + srow * LDK + shf * 16 + 8) = a1;
        *(uint4*)(Bs + srow * LDK + shf * 16)     = b0;
        *(uint4*)(Bs + srow * LDK + shf * 16 + 8) = b1;
        __syncthreads();

        v8h af[2], bf[8];
        #pragma unroll
        for (int mi = 0; mi < 2; mi++)
            af[mi] = *(const v8h*)(As + (wv * 32 + mi * 16 + r15) * LDK + q * 8);
        #pragma unroll
        for (int nj = 0; nj < 8; nj++)
            bf[nj] = *(const v8h*)(Bs + (nj * 16 + r15) * LDK + q * 8);
        #pragma unroll
        for (int mi = 0; mi < 2; mi++)
            #pragma unroll
            for (int nj = 0; nj < 8; nj++)
                acc[mi][nj] = __builtin_amdgcn_mfma_f32_16x16x32_f16(
                    af[mi], bf[nj], acc[mi][nj], 0, 0, 0);
        __syncthreads();
    }

    #pragma unroll
    for (int mi = 0; mi < 2; mi++) {
        #pragma unroll
        for (int nj = 0; nj < 8; nj++) {
            int col = gt * 128 + nj * 16 + r15;
            float bv = bias[col];
            #pragma unroll
            for (int v = 0; v < 4; v++) {
                int row = mt * 128 + wv * 32 + mi * 16 + q * 4 + v;
                float val = acc[mi][nj][v] + bv;
                gxa[row * GG + col] = f2h(val);
            }
        }
    }
}

// ---------------------------------------------------------------------------
// Kernel 2.5: pack w_h into MFMA B-fragment layout + first-reset table.
// whb dword j = ((w*48 + tile)*64 + lane)*4 + d; tiles 0..31 = zr phase
// (nt 0..3: z cols w*32+nt*16, r cols 256+w*32+(nt-2)*16; kt = tile&7),
// tiles 32..47 = a phase (cols 512+w*32+nt2*16). B-frag element j of lane l:
// W[kt*32 + (l>>4)*8 + j][colbase + (l&15)] — identical mapping to the
// (verified-working) gemm_gxa B fragment.
// Ftab[n*(NCH+1)+c] = first t >= c*WCH with reset[n][t], else TT.
// ---------------------------------------------------------------------------
__global__ __launch_bounds__(256) void pack_whb(
    const float* __restrict__ w_h, const unsigned char* __restrict__ rst,
    unsigned* __restrict__ whb, int* __restrict__ Ftab)
{
    const int bid = blockIdx.x;
    if (bid < 384) {
        int j = bid * 256 + threadIdx.x;     // dword index, 0..98303
        int w    = j / 12288;                // 48*64*4 dwords per wave
        int r    = j - w * 12288;
        int tile = r >> 8;
        int r2   = r & 255;
        int lane = r2 >> 2, d = r2 & 3;
        int r15 = lane & 15, q = lane >> 4;
        int g, k;
        if (tile < 32) {
            int nt = tile >> 3, kt = tile & 7;
            g = (nt < 2) ? (w * 32 + nt * 16 + r15)
                         : (256 + w * 32 + (nt - 2) * 16 + r15);
            k = kt * 32 + q * 8 + 2 * d;
        } else {
            int t2 = tile - 32;
            int nt2 = t2 >> 3, kt = t2 & 7;
            g = 512 + w * 32 + nt2 * 16 + r15;
            k = kt * 32 + q * 8 + 2 * d;
        }
        whb[j] = pk_rtn(w_h[k * GG + g], w_h[(k + 1) * GG + g]);
    } else {
        for (int v = threadIdx.x; v < NB * (NCH + 1); v += 256) {
            int n = v / (NCH + 1), c = v - n * (NCH + 1);
            int s = TT;
            const unsigned char* r = rst + n * TT;
            for (int t = c * WCH; t < TT; t++)
                if (r[t]) { s = t; break; }
            Ftab[v] = s;
        }
    }
}

// ---------------------------------------------------------------------------
// Kernel 3: MFMA-batched GRU scan. One block (512 thr, 8 waves) per
// (16-sequence group, 16-step window). Per step: [16x256] h-batch @ w_h on
// matrix cores. Wave w owns gate columns {z,r,a,hidden} [w*32, w*32+32):
// z and h stay lane-local (fp32 regs), only fp16 h/rh cross lanes via LDS.
// Window c starts from h=initial (valid: every masked-in t begins at a true
// reset); per-seq outputs masked to [tb,te) = [first reset >= c*W,
// first reset >= (c+1)*W). 2 barriers/step.
// ---------------------------------------------------------------------------
__global__ __launch_bounds__(512) void scan_mfma(
    const unsigned short* __restrict__ gxa, const uint4* __restrict__ whb4,
    const unsigned char* __restrict__ rst, const int* __restrict__ Ftab,
    const float* __restrict__ ihg, float* __restrict__ out)
{
    __shared__ __align__(16) unsigned short h16[SGRP * LDH];
    __shared__ __align__(16) unsigned short rh16[SGRP * LDH];
    __shared__ int s_tb[SGRP], s_te[SGRP], s_emax;

    const int tid = threadIdx.x;
    const int w = tid >> 6, lane = tid & 63;
    const int r15 = lane & 15, q = lane >> 4;
    const int grp = blockIdx.x >> 6;        // 0..3
    const int c   = blockIdx.x & (NCH - 1); // 0..63
    const int n0  = grp * SGRP;
    const int S   = c * WCH;

    // ---- weights: 48 coalesced uint4 per lane (B-fragments) ----
    uint4 wb[48];
    #pragma unroll
    for (int i = 0; i < 48; i++) wb[i] = whb4[(w * 48 + i) * 64 + lane];

    if (tid < SGRP) {
        s_tb[tid] = (c == 0) ? 0 : Ftab[(n0 + tid) * (NCH + 1) + c];
        s_te[tid] = Ftab[(n0 + tid) * (NCH + 1) + c + 1];
    }
    if (tid == 0) {   // same wave as tid<16 writers: LDS ordered in-wave
        int m = 0;
        for (int i = 0; i < SGRP; i++) m = max(m, s_te[i]);
        s_emax = m;
    }
    // init h16: (c==0 || reset at S) ? ih : 0  (pre-tb values are masked)
    for (int idx = tid; idx < SGRP * HH; idx += 512) {
        int sq = idx >> 8, jj = idx & 255;
        bool rb = (c == 0) || (rst[(n0 + sq) * TT + S] != 0);
        float v = rb ? ihg[jj] : 0.f;
        h16[sq * LDH + jj] = f2h(v);
    }
    __syncthreads();
    const int Emax = s_emax;

    const int j0 = w * 32 + r15, j1 = j0 + 16;
    const float ih0 = ihg[j0], ih1 = ihg[j1];

    int   seqi[4];    // (n0+seq)*TT row bases for this lane's 4 C-rows
    int   tbte[4];    // tb | te<<16
    float hcr[8];     // fp32 h owned by this lane: [c2*4+v] = h[seq q*4+v][j0/j1]
    #pragma unroll
    for (int v = 0; v < 4; v++) {
        int sq = q * 4 + v;
        seqi[v] = (n0 + sq) * TT;
        tbte[v] = s_tb[sq] | (s_te[sq] << 16);
        bool rb = (c == 0) || (rst[seqi[v] + S] != 0);
        hcr[v]     = rb ? ih0 : 0.f;
        hcr[4 + v] = rb ? ih1 : 0.f;
    }

    const v4f z4 = {0.f, 0.f, 0.f, 0.f};

    for (int t = S; t < Emax; t++) {
        // ---- prefetch per-step inputs (consumed in epilogues) ----
        unsigned short gz[16];
        #pragma unroll
        for (int v = 0; v < 4; v++) {
            const unsigned short* gp = gxa + (size_t)(seqi[v] + t) * GG;
            gz[v]      = gp[j0];          // z, col j0
            gz[4 + v]  = gp[j1];          // z, col j1
            gz[8 + v]  = gp[256 + j0];    // r, col j0
            gz[12 + v] = gp[256 + j1];    // r, col j1
        }
        int tn = (t + 1 < TT) ? (t + 1) : (TT - 1);
        unsigned char rn[4];
        #pragma unroll
        for (int v = 0; v < 4; v++) rn[v] = rst[seqi[v] + tn];

        // ---- phase 1: zr = h @ Wzr  (32 MFMAs/wave) ----
        v4f az0 = z4, az1 = z4, ar0 = z4, ar1 = z4;
        #pragma unroll
        for (int kt = 0; kt < 8; kt++) {
            v8h af = *(const v8h*)(h16 + r15 * LDH + kt * 32 + q * 8);
            az0 = __builtin_amdgcn_mfma_f32_16x16x32_f16(af, __builtin_bit_cast(v8h, wb[kt]),      az0, 0, 0, 0);
            az1 = __builtin_amdgcn_mfma_f32_16x16x32_f16(af, __builtin_bit_cast(v8h, wb[8 + kt]),  az1, 0, 0, 0);
            ar0 = __builtin_amdgcn_mfma_f32_16x16x32_f16(af, __builtin_bit_cast(v8h, wb[16 + kt]), ar0, 0, 0, 0);
            ar1 = __builtin_amdgcn_mfma_f32_16x16x32_f16(af, __builtin_bit_cast(v8h, wb[24 + kt]), ar1, 0, 0, 0);
        }

        // ---- epilogue 1: sigmoid; z kept local; rh -> LDS (fp16) ----
        float zs[8];
        #pragma unroll
        for (int v = 0; v < 4; v++) {
            float z0 = az0[v] + h2f(gz[v]);
            float z1 = az1[v] + h2f(gz[4 + v]);
            zs[v]     = 1.f / (1.f + __expf(-z0));
            zs[4 + v] = 1.f / (1.f + __expf(-z1));
            float r0 = ar0[v] + h2f(gz[8 + v]);
            float r1 = ar1[v] + h2f(gz[12 + v]);
            float s0 = 1.f / (1.f + __expf(-r0));
            float s1 = 1.f / (1.f + __expf(-r1));
            int sq = q * 4 + v;
            rh16[sq * LDH + j0] = f2h(s0 * hcr[v]);
            rh16[sq * LDH + j1] = f2h(s1 * hcr[4 + v]);
        }
        __syncthreads();   // B1: rh16 ready

        // ---- phase 2: a = rh @ Wa  (16 MFMAs/wave) ----
        unsigned short gav[8];
        #pragma unroll
        for (int v = 0; v < 4; v++) {
            const unsigned short* gp = gxa + (size_t)(seqi[v] + t) * GG + 512;
            gav[v]     = gp[j0];
            gav[4 + v] = gp[j1];
        }
        v4f aa0 = z4, aa1 = z4;
        #pragma unroll
        for (int kt = 0; kt < 8; kt++) {
            v8h af = *(const v8h*)(rh16 + r15 * LDH + kt * 32 + q * 8);
            aa0 = __builtin_amdgcn_mfma_f32_16x16x32_f16(af, __builtin_bit_cast(v8h, wb[32 + kt]), aa0, 0, 0, 0);
            aa1 = __builtin_amdgcn_mfma_f32_16x16x32_f16(af, __builtin_bit_cast(v8h, wb[40 + kt]), aa1, 0, 0, 0);
        }

        // ---- epilogue 2: tanh, state update, masked store, next reset ----
        #pragma unroll
        for (int v = 0; v < 4; v++) {
            int sq = q * 4 + v;
            int tb = tbte[v] & 0xFFFF, te = tbte[v] >> 16;
            bool wr = (t >= tb) && (t < te);
            int mo = (seqi[v] + t) * HH;
            float u0 = aa0[v] + h2f(gav[v]);
            float u1 = aa1[v] + h2f(gav[4 + v]);
            float e0 = __expf(2.f * u0), e1 = __expf(2.f * u1);
            float t0 = (e0 - 1.f) / (e0 + 1.f);
            float t1 = (e1 - 1.f) / (e1 + 1.f);
            float hn0 = hcr[v]     + zs[v]     * (t0 - hcr[v]);
            float hn1 = hcr[4 + v] + zs[4 + v] * (t1 - hcr[4 + v]);
            if (wr) {
                out[mo + j0] = hn0;
                out[mo + j1] = hn1;
                out[MM * HH + mo + j0] = hn0;
                out[MM * HH + mo + j1] = hn1;
            }
            bool rb = rn[v] != 0;
            float g0 = rb ? ih0 : hn0;
            float g1 = rb ? ih1 : hn1;
            hcr[v] = g0; hcr[4 + v] = g1;
            h16[sq * LDH + j0] = f2h(g0);
            h16[sq * LDH + j1] = f2h(g1);
        }
        __syncthreads();   // B2: h16 ready for next step
    }
}

// ---------------------------------------------------------------------------
extern "C" void kernel_launch(void* const* d_in, const int* in_sizes, int n_in,
                              void* d_out, int out_size, void* d_ws, size_t ws_size,
                              hipStream_t stream)
{
    const float* x   = (const float*)d_in[0];
    const float* a   = (const float*)d_in[1];
    const void*  rsv = d_in[2];
    const float* w_i = (const float*)d_in[3];
    const float* w_h = (const float*)d_in[4];
    const float* w_a = (const float*)d_in[5];
    const float* b   = (const float*)d_in[6];
    const float* ih  = (const float*)d_in[7];
    float*       out = (float*)d_out;

    char* ws = (char*)d_ws;
    unsigned short* gxa  = (unsigned short*)ws;                                  // MM*GG fp16 (96 MB)
    unsigned short* xa   = (unsigned short*)(ws + (size_t)MM * GG * 2);          // MM*KP fp16 (37.7 MB)
    unsigned short* wt   = (unsigned short*)(ws + (size_t)MM * GG * 2
                                                + (size_t)MM * KP * 2);          // GG*KP fp16 (0.44 MB)
    unsigned char*  rst8 = (unsigned char*)(ws + (size_t)MM * GG * 2
                                               + (size_t)MM * KP * 2
                                               + (size_t)GG * KP * 2);           // 64 KB canonical resets
    // whb + Ftab overlap the xa region (dead after gemm_gxa); written by
    // pack_whb which runs after the GEMM. No workspace growth.
    unsigned* whb  = (unsigned*)xa;                                              // 98304 dwords (384 KB)
    int*      Ftab = (int*)(ws + (size_t)MM * GG * 2 + 98304u * 4);              // 64*65 ints

    fix_reset<<<1, 1024, 0, stream>>>((const unsigned*)rsv, rst8);

    int total = MM * KP + GG * KP + HH;
    int pblocks = (total + 255) / 256;
    prepass<<<pblocks, 256, 0, stream>>>(x, a, w_i, w_a, ih,
                                         out + (size_t)2 * MM * HH, xa, wt);
    gemm_gxa<<<512 * 6, 256, 0, stream>>>(xa, wt, b, gxa);
    pack_whb<<<385, 256, 0, stream>>>(w_h, rst8, whb, Ftab);
    scan_mfma<<<(NB / SGRP) * NCH, 512, 0, stream>>>(
        gxa, (const uint4*)whb, rst8, Ftab, ih, out);
}

// Round 3
// 461.633 us; speedup vs baseline: 4.1835x; 1.0599x over previous
//
#include <hip/hip_runtime.h>
#include <hip/hip_fp16.h>

#define NB 64
#define TT 1024
#define FF 256
#define HH 256
#define GG 768
#define AA 8
#define KP 288          // padded K: 256 (x) + 8 (a) + 24 zeros
#define MM (NB*TT)      // 65536 rows
#define SGRP 16         // sequences batched per scan block (MFMA M=16)
#define WCH 16          // time-window per chunk
#define NCH (TT/WCH)    // 64 chunks
#define LDH 264         // LDS row stride (halfs) for h16/rh16
#define GSP 776         // LDS row stride (halfs) for staged gxa rows (768+8)

typedef _Float16 h2v __attribute__((ext_vector_type(2)));
typedef _Float16 v8h __attribute__((ext_vector_type(8)));
typedef float    v4f __attribute__((ext_vector_type(4)));

static __device__ __forceinline__ unsigned pk_rtn(float a, float b) {
    unsigned lo = (unsigned)__half_as_ushort(__float2half(a));
    unsigned hi = (unsigned)__half_as_ushort(__float2half(b));
    return lo | (hi << 16);
}
static __device__ __forceinline__ float h2f(unsigned short u) {
    return (float)__builtin_bit_cast(_Float16, u);
}
static __device__ __forceinline__ unsigned short f2h(float f) {
    return __half_as_ushort(__float2half(f));
}

// ---------------------------------------------------------------------------
// Kernel 0: robust reset-dtype detection + canonicalization to uint8.
// (unchanged)
// ---------------------------------------------------------------------------
__global__ __launch_bounds__(1024) void fix_reset(
    const unsigned* __restrict__ src, unsigned char* __restrict__ dst)
{
    __shared__ unsigned red[16];
    const int tid = threadIdx.x;

    unsigned acc = 0;
    #pragma unroll
    for (int i = 0; i < 16; i++)
        acc |= src[tid * 16 + i] & 0xFFFFFF00u;
    #pragma unroll
    for (int off = 32; off >= 1; off >>= 1)
        acc |= __shfl_down(acc, off, 64);
    if ((tid & 63) == 0) red[tid >> 6] = acc;
    __syncthreads();
    unsigned flag = 0;
    #pragma unroll
    for (int i = 0; i < 16; i++) flag |= red[i];
    const bool is_i32 = (flag == 0);

    if (is_i32) {
        const int per = (NB * TT) / 1024;   // 64
        #pragma unroll
        for (int i = 0; i < per; i++) {
            int idx = tid * per + i;
            dst[idx] = (unsigned char)(src[idx] != 0 ? 1 : 0);
        }
    } else {
        unsigned* d4 = (unsigned*)dst;
        #pragma unroll
        for (int i = 0; i < 16; i++)
            d4[tid * 16 + i] = src[tid * 16 + i];
    }
}

// ---------------------------------------------------------------------------
// Kernel 1: build transposed padded weights wt[GG][KP] fp16 + output #3.
// (the xa build is now fused into gemm_fused; this is the tiny remainder)
// ---------------------------------------------------------------------------
__global__ __launch_bounds__(256) void wt_build(
    const float* __restrict__ w_i, const float* __restrict__ w_a,
    const float* __restrict__ ihg, float* __restrict__ out3,
    unsigned short* __restrict__ wt)
{
    int idx = blockIdx.x * 256 + threadIdx.x;
    const int E2 = GG * KP;          // 221,184
    if (idx < E2) {
        int g = idx / KP, k = idx - g * KP;
        float v = 0.f;
        if (k < FF)            v = w_i[k * GG + g];
        else if (k < FF + AA)  v = w_a[(k - FF) * GG + g];
        wt[idx] = f2h(v);
    } else if (idx < E2 + HH) {
        int i = idx - E2;
        out3[i] = ihg[i];
    }
}

// ---------------------------------------------------------------------------
// Kernel 2: gxa[MM][GG] (fp16) = [x|a|0] @ W + bias, with on-the-fly f32->fp16
// conversion of x/a during A staging (bit-identical f2h path to the old
// prepass). Saves the 37.7MB xa round-trip and a full dispatch.
// ---------------------------------------------------------------------------
#define LDK 40

__global__ __launch_bounds__(256) void gemm_fused(
    const float* __restrict__ x, const float* __restrict__ a,
    const unsigned short* __restrict__ wt,
    const float* __restrict__ bias, unsigned short* __restrict__ gxa)
{
    __shared__ __align__(16) unsigned short As[128 * LDK];
    __shared__ __align__(16) unsigned short Bs[128 * LDK];

    const int bid = blockIdx.x;
    const int gt = bid % 6, mt = bid / 6;
    const int tid = threadIdx.x;
    const int lane = tid & 63, wv = tid >> 6;
    const int srow = tid & 127, shf = tid >> 7;
    const int r15 = lane & 15, q = lane >> 4;

    v4f acc[2][8];
    #pragma unroll
    for (int i = 0; i < 2; i++)
        #pragma unroll
        for (int j = 0; j < 8; j++) acc[i][j] = (v4f){0.f, 0.f, 0.f, 0.f};

    const int arow = mt * 128 + srow;

    for (int kc = 0; kc < 9; kc++) {
        // ---- A: 16 k-values from x/a (f32), convert to fp16 in regs ----
        uint4 A0, A1;
        if (kc < 8) {
            const float4* sp = (const float4*)(x + (size_t)arow * FF + kc * 32 + shf * 16);
            float4 f0 = sp[0], f1 = sp[1], f2 = sp[2], f3 = sp[3];
            A0.x = pk_rtn(f0.x, f0.y); A0.y = pk_rtn(f0.z, f0.w);
            A0.z = pk_rtn(f1.x, f1.y); A0.w = pk_rtn(f1.z, f1.w);
            A1.x = pk_rtn(f2.x, f2.y); A1.y = pk_rtn(f2.z, f2.w);
            A1.z = pk_rtn(f3.x, f3.y); A1.w = pk_rtn(f3.z, f3.w);
        } else if (shf == 0) {       // k in [256,272): first 8 from a, rest 0
            const float4* ap = (const float4*)(a + (size_t)arow * AA);
            float4 f0 = ap[0], f1 = ap[1];
            A0.x = pk_rtn(f0.x, f0.y); A0.y = pk_rtn(f0.z, f0.w);
            A0.z = pk_rtn(f1.x, f1.y); A0.w = pk_rtn(f1.z, f1.w);
            A1 = (uint4){0, 0, 0, 0};
        } else {                      // k in [272,288): zeros
            A0 = (uint4){0, 0, 0, 0};
            A1 = (uint4){0, 0, 0, 0};
        }
        // ---- B: fp16 weights as before ----
        const uint4* srcB = (const uint4*)(wt + (gt * 128 + srow) * KP + kc * 32 + shf * 16);
        uint4 b0 = srcB[0], b1 = srcB[1];

        *(uint4*)(As + srow * LDK + shf * 16)     = A0;
        *(uint4*)(As + srow * LDK + shf * 16 + 8) = A1;
        *(uint4*)(Bs + srow * LDK + shf * 16)     = b0;
        *(uint4*)(Bs + srow * LDK + shf * 16 + 8) = b1;
        __syncthreads();

        v8h af[2], bf[8];
        #pragma unroll
        for (int mi = 0; mi < 2; mi++)
            af[mi] = *(const v8h*)(As + (wv * 32 + mi * 16 + r15) * LDK + q * 8);
        #pragma unroll
        for (int nj = 0; nj < 8; nj++)
            bf[nj] = *(const v8h*)(Bs + (nj * 16 + r15) * LDK + q * 8);
        #pragma unroll
        for (int mi = 0; mi < 2; mi++)
            #pragma unroll
            for (int nj = 0; nj < 8; nj++)
                acc[mi][nj] = __builtin_amdgcn_mfma_f32_16x16x32_f16(
                    af[mi], bf[nj], acc[mi][nj], 0, 0, 0);
        __syncthreads();
    }

    #pragma unroll
    for (int mi = 0; mi < 2; mi++) {
        #pragma unroll
        for (int nj = 0; nj < 8; nj++) {
            int col = gt * 128 + nj * 16 + r15;
            float bv = bias[col];
            #pragma unroll
            for (int v = 0; v < 4; v++) {
                int row = mt * 128 + wv * 32 + mi * 16 + q * 4 + v;
                float val = acc[mi][nj][v] + bv;
                gxa[row * GG + col] = f2h(val);
            }
        }
    }
}

// ---------------------------------------------------------------------------
// Kernel 2.5: pack w_h into MFMA B-fragment layout + first-reset table.
// (unchanged mapping; now launched before the GEMM — no aliasing)
// ---------------------------------------------------------------------------
__global__ __launch_bounds__(256) void pack_whb(
    const float* __restrict__ w_h, const unsigned char* __restrict__ rst,
    unsigned* __restrict__ whb, int* __restrict__ Ftab)
{
    const int bid = blockIdx.x;
    if (bid < 384) {
        int j = bid * 256 + threadIdx.x;     // dword index, 0..98303
        int w    = j / 12288;                // 48*64*4 dwords per wave
        int r    = j - w * 12288;
        int tile = r >> 8;
        int r2   = r & 255;
        int lane = r2 >> 2, d = r2 & 3;
        int r15 = lane & 15, q = lane >> 4;
        int g, k;
        if (tile < 32) {
            int nt = tile >> 3, kt = tile & 7;
            g = (nt < 2) ? (w * 32 + nt * 16 + r15)
                         : (256 + w * 32 + (nt - 2) * 16 + r15);
            k = kt * 32 + q * 8 + 2 * d;
        } else {
            int t2 = tile - 32;
            int nt2 = t2 >> 3, kt = t2 & 7;
            g = 512 + w * 32 + nt2 * 16 + r15;
            k = kt * 32 + q * 8 + 2 * d;
        }
        whb[j] = pk_rtn(w_h[k * GG + g], w_h[(k + 1) * GG + g]);
    } else {
        for (int v = threadIdx.x; v < NB * (NCH + 1); v += 256) {
            int n = v / (NCH + 1), c = v - n * (NCH + 1);
            int s = TT;
            const unsigned char* r = rst + n * TT;
            for (int t = c * WCH; t < TT; t++)
                if (r[t]) { s = t; break; }
            Ftab[v] = s;
        }
    }
}

// ---------------------------------------------------------------------------
// Kernel 3: MFMA-batched GRU scan, spill-free + LDS-staged inputs.
//  - __launch_bounds__(512,2): 256-reg budget (was silently capped at 128
//    and spilling the weight fragments to scratch every step).
//  - 40 of 48 weight B-fragments in regs (160 dwords); the 8 aa1 tiles live
//    in LDS (64 KB), read as conflict-free lane-contiguous ds_read_b128.
//  - gxa rows for the 16 seqs staged to LDS, double-buffered: 3 coalesced
//    uint4 global loads/thread issued at step top, ds_writes at step bottom
//    (T14 async split) — latency hidden under the whole step.
// ---------------------------------------------------------------------------
__global__ __launch_bounds__(512, 2) void scan_mfma(
    const unsigned short* __restrict__ gxa, const uint4* __restrict__ whb4,
    const unsigned char* __restrict__ rst, const int* __restrict__ Ftab,
    const float* __restrict__ ihg, float* __restrict__ out)
{
    __shared__ __align__(16) unsigned short h16[SGRP * LDH];
    __shared__ __align__(16) unsigned short rh16[SGRP * LDH];
    __shared__ __align__(16) unsigned short gstage[2][SGRP * GSP];
    __shared__ __align__(16) uint4 waL[8 * 8 * 64];   // aa1 tiles [w][kt][lane]
    __shared__ int s_tb[SGRP], s_te[SGRP], s_emax;

    const int tid = threadIdx.x;
    const int w = tid >> 6, lane = tid & 63;
    const int r15 = lane & 15, q = lane >> 4;
    const int grp = blockIdx.x >> 6;        // 0..3
    const int c   = blockIdx.x & (NCH - 1); // 0..63
    const int n0  = grp * SGRP;
    const int S   = c * WCH;

    // ---- weights: 40 reg fragments + 8 LDS fragments per wave ----
    uint4 wb[40];
    #pragma unroll
    for (int i = 0; i < 40; i++) wb[i] = whb4[(w * 48 + i) * 64 + lane];
    #pragma unroll
    for (int rr = 0; rr < 8; rr++) {
        int f = rr * 512 + tid;             // [w=rr][kt=tid>>6][lane=tid&63]
        waL[f] = whb4[(rr * 48 + 40 + (tid >> 6)) * 64 + (tid & 63)];
    }

    if (tid < SGRP) {
        s_tb[tid] = (c == 0) ? 0 : Ftab[(n0 + tid) * (NCH + 1) + c];
        s_te[tid] = Ftab[(n0 + tid) * (NCH + 1) + c + 1];
    }
    if (tid == 0) {   // same wave as tid<16 writers: in-wave LDS ordering
        int m = 0;
        for (int i = 0; i < SGRP; i++) m = max(m, s_te[i]);
        s_emax = m;
    }
    // init h16: (c==0 || reset at S) ? ih : 0  (pre-tb values are masked)
    for (int idx = tid; idx < SGRP * HH; idx += 512) {
        int sq = idx >> 8, jj = idx & 255;
        bool rb = (c == 0) || (rst[(n0 + sq) * TT + S] != 0);
        float v = rb ? ihg[jj] : 0.f;
        h16[sq * LDH + jj] = f2h(v);
    }
    // initial gxa stage for t = S
    const int seqS = tid >> 5, jS = tid & 31;
    {
        const uint4* sp = (const uint4*)(gxa + ((size_t)(n0 + seqS) * TT + S) * GG);
        uint4 g0 = sp[jS], g1 = sp[jS + 32], g2 = sp[jS + 64];
        uint4* dp = (uint4*)(gstage[0] + seqS * GSP);
        dp[jS] = g0; dp[jS + 32] = g1; dp[jS + 64] = g2;
    }
    __syncthreads();
    const int Emax = s_emax;

    const int j0 = w * 32 + r15, j1 = j0 + 16;
    const float ih0 = ihg[j0], ih1 = ihg[j1];

    int   seqi[4];    // (n0+seq)*TT row bases for this lane's 4 C-rows
    int   tbte[4];    // tb | te<<16
    float hcr[8];     // fp32 h owned by this lane
    #pragma unroll
    for (int v = 0; v < 4; v++) {
        int sq = q * 4 + v;
        seqi[v] = (n0 + sq) * TT;
        tbte[v] = s_tb[sq] | (s_te[sq] << 16);
        bool rb = (c == 0) || (rst[seqi[v] + S] != 0);
        hcr[v]     = rb ? ih0 : 0.f;
        hcr[4 + v] = rb ? ih1 : 0.f;
    }

    const v4f z4 = {0.f, 0.f, 0.f, 0.f};

    for (int t = S; t < Emax; t++) {
        const int cur = (t - S) & 1, nxt = cur ^ 1;
        const int tn = (t + 1 < TT) ? (t + 1) : (TT - 1);

        // ---- issue next-step global loads (drain at step bottom) ----
        uint4 g0, g1, g2;
        {
            const uint4* sp = (const uint4*)(gxa + ((size_t)(n0 + seqS) * TT + tn) * GG);
            g0 = sp[jS]; g1 = sp[jS + 32]; g2 = sp[jS + 64];
        }
        unsigned char rn[4];
        #pragma unroll
        for (int v = 0; v < 4; v++) rn[v] = rst[seqi[v] + tn];

        // ---- phase 1: zr = h @ Wzr  (32 MFMAs/wave) ----
        v4f az0 = z4, az1 = z4, ar0 = z4, ar1 = z4;
        #pragma unroll
        for (int kt = 0; kt < 8; kt++) {
            v8h af = *(const v8h*)(h16 + r15 * LDH + kt * 32 + q * 8);
            az0 = __builtin_amdgcn_mfma_f32_16x16x32_f16(af, __builtin_bit_cast(v8h, wb[kt]),      az0, 0, 0, 0);
            az1 = __builtin_amdgcn_mfma_f32_16x16x32_f16(af, __builtin_bit_cast(v8h, wb[8 + kt]),  az1, 0, 0, 0);
            ar0 = __builtin_amdgcn_mfma_f32_16x16x32_f16(af, __builtin_bit_cast(v8h, wb[16 + kt]), ar0, 0, 0, 0);
            ar1 = __builtin_amdgcn_mfma_f32_16x16x32_f16(af, __builtin_bit_cast(v8h, wb[24 + kt]), ar1, 0, 0, 0);
        }

        // ---- epilogue 1: sigmoid; z kept local; rh -> LDS (fp16) ----
        const unsigned short* gs = gstage[cur];
        float zs[8];
        #pragma unroll
        for (int v = 0; v < 4; v++) {
            int sq = q * 4 + v;
            int gb = sq * GSP;
            float z0 = az0[v] + h2f(gs[gb + j0]);
            float z1 = az1[v] + h2f(gs[gb + j1]);
            zs[v]     = 1.f / (1.f + __expf(-z0));
            zs[4 + v] = 1.f / (1.f + __expf(-z1));
            float r0 = ar0[v] + h2f(gs[gb + 256 + j0]);
            float r1 = ar1[v] + h2f(gs[gb + 256 + j1]);
            float s0 = 1.f / (1.f + __expf(-r0));
            float s1 = 1.f / (1.f + __expf(-r1));
            rh16[sq * LDH + j0] = f2h(s0 * hcr[v]);
            rh16[sq * LDH + j1] = f2h(s1 * hcr[4 + v]);
        }
        __syncthreads();   // B1: rh16 ready

        // ---- phase 2: a = rh @ Wa  (16 MFMAs/wave, 8 B-frags from LDS) ----
        v4f aa0 = z4, aa1 = z4;
        #pragma unroll
        for (int kt = 0; kt < 8; kt++) {
            v8h af = *(const v8h*)(rh16 + r15 * LDH + kt * 32 + q * 8);
            uint4 wv4 = waL[(w * 8 + kt) * 64 + lane];
            aa0 = __builtin_amdgcn_mfma_f32_16x16x32_f16(af, __builtin_bit_cast(v8h, wb[32 + kt]), aa0, 0, 0, 0);
            aa1 = __builtin_amdgcn_mfma_f32_16x16x32_f16(af, __builtin_bit_cast(v8h, wv4),         aa1, 0, 0, 0);
        }

        // ---- epilogue 2: tanh, state update, masked store, next reset ----
        #pragma unroll
        for (int v = 0; v < 4; v++) {
            int sq = q * 4 + v;
            int gb = sq * GSP;
            int tb = tbte[v] & 0xFFFF, te = tbte[v] >> 16;
            bool wr = (t >= tb) && (t < te);
            int mo = (seqi[v] + t) * HH;
            float u0 = aa0[v] + h2f(gs[gb + 512 + j0]);
            float u1 = aa1[v] + h2f(gs[gb + 512 + j1]);
            float e0 = __expf(2.f * u0), e1 = __expf(2.f * u1);
            float t0 = (e0 - 1.f) / (e0 + 1.f);
            float t1 = (e1 - 1.f) / (e1 + 1.f);
            float hn0 = hcr[v]     + zs[v]     * (t0 - hcr[v]);
            float hn1 = hcr[4 + v] + zs[4 + v] * (t1 - hcr[4 + v]);
            if (wr) {
                out[mo + j0] = hn0;
                out[mo + j1] = hn1;
                out[MM * HH + mo + j0] = hn0;
                out[MM * HH + mo + j1] = hn1;
            }
            bool rb = rn[v] != 0;
            float g0f = rb ? ih0 : hn0;
            float g1f = rb ? ih1 : hn1;
            hcr[v] = g0f; hcr[4 + v] = g1f;
            h16[sq * LDH + j0] = f2h(g0f);
            h16[sq * LDH + j1] = f2h(g1f);
        }

        // ---- write staged gxa for t+1 (loads drained here, not earlier) ----
        {
            uint4* dp = (uint4*)(gstage[nxt] + seqS * GSP);
            dp[jS] = g0; dp[jS + 32] = g1; dp[jS + 64] = g2;
        }
        __syncthreads();   // B2: h16 + gstage[nxt] ready for next step
    }
}

// ---------------------------------------------------------------------------
extern "C" void kernel_launch(void* const* d_in, const int* in_sizes, int n_in,
                              void* d_out, int out_size, void* d_ws, size_t ws_size,
                              hipStream_t stream)
{
    const float* x   = (const float*)d_in[0];
    const float* a   = (const float*)d_in[1];
    const void*  rsv = d_in[2];
    const float* w_i = (const float*)d_in[3];
    const float* w_h = (const float*)d_in[4];
    const float* w_a = (const float*)d_in[5];
    const float* b   = (const float*)d_in[6];
    const float* ih  = (const float*)d_in[7];
    float*       out = (float*)d_out;

    char* ws = (char*)d_ws;
    size_t o = 0;
    unsigned short* gxa  = (unsigned short*)(ws + o); o += (size_t)MM * GG * 2;  // 96 MB
    unsigned short* wt   = (unsigned short*)(ws + o); o += (size_t)GG * KP * 2;  // 0.44 MB
    unsigned char*  rst8 = (unsigned char*) (ws + o); o += (size_t)NB * TT;      // 64 KB
    unsigned*       whb  = (unsigned*)      (ws + o); o += 98304u * 4;           // 384 KB
    int*            Ftab = (int*)           (ws + o);                            // 16.6 KB

    fix_reset<<<1, 1024, 0, stream>>>((const unsigned*)rsv, rst8);

    int wtb = (GG * KP + HH + 255) / 256;
    wt_build<<<wtb, 256, 0, stream>>>(w_i, w_a, ih, out + (size_t)2 * MM * HH, wt);

    pack_whb<<<385, 256, 0, stream>>>(w_h, rst8, whb, Ftab);

    gemm_fused<<<512 * 6, 256, 0, stream>>>(x, a, wt, b, gxa);

    scan_mfma<<<(NB / SGRP) * NCH, 512, 0, stream>>>(
        gxa, (const uint4*)whb, rst8, Ftab, ih, out);
}

// Round 4
// 422.219 us; speedup vs baseline: 4.5740x; 1.0934x over previous
//
#include <hip/hip_runtime.h>
#include <hip/hip_fp16.h>

#define NB 64
#define TT 1024
#define FF 256
#define HH 256
#define GG 768
#define AA 8
#define KP 288          // padded K: 256 (x) + 8 (a) + 24 zeros
#define MM (NB*TT)      // 65536 rows
#define SGRP 16         // sequences batched per scan block (MFMA M=16)
#define WCH 16          // time-window per chunk
#define NCH (TT/WCH)    // 64 chunks
#define LDH 264         // LDS row stride (halfs) for h16/rh16
#define GSP 776         // LDS row stride (halfs) for staged gxa rows (768+8)

typedef _Float16 h2v __attribute__((ext_vector_type(2)));
typedef _Float16 v8h __attribute__((ext_vector_type(8)));
typedef float    v4f __attribute__((ext_vector_type(4)));

static __device__ __forceinline__ unsigned pk_rtn(float a, float b) {
    unsigned lo = (unsigned)__half_as_ushort(__float2half(a));
    unsigned hi = (unsigned)__half_as_ushort(__float2half(b));
    return lo | (hi << 16);
}
static __device__ __forceinline__ float h2f(unsigned short u) {
    return (float)__builtin_bit_cast(_Float16, u);
}
static __device__ __forceinline__ unsigned short f2h(float f) {
    return __half_as_ushort(__float2half(f));
}

// ---------------------------------------------------------------------------
// Kernel 0: reset-dtype detection + canonicalization to uint8, PLUS the
// first-reset table Ftab[n*(NCH+1)+c] = first t >= c*WCH with reset[n][t]
// (else TT). Single block; __syncthreads (full vmcnt drain) orders the
// rst8 writes before the Ftab scan reads them.
// ---------------------------------------------------------------------------
__global__ __launch_bounds__(1024) void fix_reset(
    const unsigned* __restrict__ src, unsigned char* __restrict__ dst,
    int* __restrict__ Ftab)
{
    __shared__ unsigned red[16];
    const int tid = threadIdx.x;

    unsigned acc = 0;
    #pragma unroll
    for (int i = 0; i < 16; i++)
        acc |= src[tid * 16 + i] & 0xFFFFFF00u;
    #pragma unroll
    for (int off = 32; off >= 1; off >>= 1)
        acc |= __shfl_down(acc, off, 64);
    if ((tid & 63) == 0) red[tid >> 6] = acc;
    __syncthreads();
    unsigned flag = 0;
    #pragma unroll
    for (int i = 0; i < 16; i++) flag |= red[i];
    const bool is_i32 = (flag == 0);

    if (is_i32) {
        const int per = (NB * TT) / 1024;   // 64
        #pragma unroll
        for (int i = 0; i < per; i++) {
            int idx = tid * per + i;
            dst[idx] = (unsigned char)(src[idx] != 0 ? 1 : 0);
        }
    } else {
        unsigned* d4 = (unsigned*)dst;
        #pragma unroll
        for (int i = 0; i < 16; i++)
            d4[tid * 16 + i] = src[tid * 16 + i];
    }
    __syncthreads();   // rst8 fully written & drained before Ftab scan

    for (int v = tid; v < NB * (NCH + 1); v += 1024) {
        int n = v / (NCH + 1), c = v - n * (NCH + 1);
        int s = TT;
        const unsigned char* r = dst + n * TT;
        for (int t = c * WCH; t < TT; t++)
            if (r[t]) { s = t; break; }
        Ftab[v] = s;
    }
}

// ---------------------------------------------------------------------------
// Kernel 1: merged weight prep.
// Blocks [0,865): wt[GG][KP] fp16 transpose-pad + out3 copy.
// Blocks [865,1249): whb MFMA B-fragment pack of w_h (mapping identical to
// the verified pack_whb).
// ---------------------------------------------------------------------------
__global__ __launch_bounds__(256) void prep_weights(
    const float* __restrict__ w_i, const float* __restrict__ w_a,
    const float* __restrict__ w_h, const float* __restrict__ ihg,
    float* __restrict__ out3,
    unsigned short* __restrict__ wt, unsigned* __restrict__ whb)
{
    const int bid = blockIdx.x;
    if (bid < 865) {
        int idx = bid * 256 + threadIdx.x;
        const int E2 = GG * KP;          // 221,184
        if (idx < E2) {
            int g = idx / KP, k = idx - g * KP;
            float v = 0.f;
            if (k < FF)            v = w_i[k * GG + g];
            else if (k < FF + AA)  v = w_a[(k - FF) * GG + g];
            wt[idx] = f2h(v);
        } else if (idx < E2 + HH) {
            int i = idx - E2;
            out3[i] = ihg[i];
        }
    } else {
        int j = (bid - 865) * 256 + threadIdx.x;   // dword index, 0..98303
        int w    = j / 12288;                      // 48*64*4 dwords per wave
        int r    = j - w * 12288;
        int tile = r >> 8;
        int r2   = r & 255;
        int lane = r2 >> 2, d = r2 & 3;
        int r15 = lane & 15, q = lane >> 4;
        int g, k;
        if (tile < 32) {
            int nt = tile >> 3, kt = tile & 7;
            g = (nt < 2) ? (w * 32 + nt * 16 + r15)
                         : (256 + w * 32 + (nt - 2) * 16 + r15);
            k = kt * 32 + q * 8 + 2 * d;
        } else {
            int t2 = tile - 32;
            int nt2 = t2 >> 3, kt = t2 & 7;
            g = 512 + w * 32 + nt2 * 16 + r15;
            k = kt * 32 + q * 8 + 2 * d;
        }
        whb[j] = pk_rtn(w_h[k * GG + g], w_h[(k + 1) * GG + g]);
    }
}

// ---------------------------------------------------------------------------
// Kernel 2: gxa[MM][GG] (fp16) = [x|a|0] @ W + bias.
//  - XCD-bijective blockIdx swizzle: wg = (bid&7)*384 + (bid>>3). Each XCD
//    gets a contiguous run of logical ids -> the 6 gt-tiles of one mt strip
//    are co-resident on ONE XCD, so the x strip is fetched from HBM once
//    and re-served from that XCD's L2 (was 3.1x over-fetch, 205MB).
//  - Double-buffered LDS + register prefetch: issue kc+1 global loads
//    before kc's MFMAs, commit to the other buffer after -> ONE barrier
//    per kc (was 2), loads stay in flight across the barrier.
// ---------------------------------------------------------------------------
#define LDK 40

__global__ __launch_bounds__(256, 3) void gemm_fused(
    const float* __restrict__ x, const float* __restrict__ a,
    const unsigned short* __restrict__ wt,
    const float* __restrict__ bias, unsigned short* __restrict__ gxa)
{
    __shared__ __align__(16) unsigned short As[2][128 * LDK];
    __shared__ __align__(16) unsigned short Bs[2][128 * LDK];

    const int bid = blockIdx.x;
    const int wg  = (bid & 7) * 384 + (bid >> 3);   // bijective, 3072 % 8 == 0
    const int gt = wg % 6, mt = wg / 6;
    const int tid = threadIdx.x;
    const int lane = tid & 63, wv = tid >> 6;
    const int srow = tid & 127, shf = tid >> 7;
    const int r15 = lane & 15, q = lane >> 4;

    v4f acc[2][8];
    #pragma unroll
    for (int i = 0; i < 2; i++)
        #pragma unroll
        for (int j = 0; j < 8; j++) acc[i][j] = (v4f){0.f, 0.f, 0.f, 0.f};

    const int arow = mt * 128 + srow;
    const int brow = gt * 128 + srow;

    float4 f0, f1, f2, f3;
    uint4  pb0, pb1;

    auto issue = [&](int kc) {
        if (kc < 8) {
            const float4* sp = (const float4*)(x + (size_t)arow * FF + kc * 32 + shf * 16);
            f0 = sp[0]; f1 = sp[1]; f2 = sp[2]; f3 = sp[3];
        } else if (shf == 0) {
            const float4* ap = (const float4*)(a + (size_t)arow * AA);
            f0 = ap[0]; f1 = ap[1];
        }
        const uint4* srcB = (const uint4*)(wt + brow * KP + kc * 32 + shf * 16);
        pb0 = srcB[0]; pb1 = srcB[1];
    };
    auto commit = [&](int buf, int kc) {
        uint4 A0, A1;
        if (kc < 8) {
            A0.x = pk_rtn(f0.x, f0.y); A0.y = pk_rtn(f0.z, f0.w);
            A0.z = pk_rtn(f1.x, f1.y); A0.w = pk_rtn(f1.z, f1.w);
            A1.x = pk_rtn(f2.x, f2.y); A1.y = pk_rtn(f2.z, f2.w);
            A1.z = pk_rtn(f3.x, f3.y); A1.w = pk_rtn(f3.z, f3.w);
        } else {
            if (shf == 0) {
                A0.x = pk_rtn(f0.x, f0.y); A0.y = pk_rtn(f0.z, f0.w);
                A0.z = pk_rtn(f1.x, f1.y); A0.w = pk_rtn(f1.z, f1.w);
            } else {
                A0 = (uint4){0, 0, 0, 0};
            }
            A1 = (uint4){0, 0, 0, 0};
        }
        *(uint4*)(As[buf] + srow * LDK + shf * 16)     = A0;
        *(uint4*)(As[buf] + srow * LDK + shf * 16 + 8) = A1;
        *(uint4*)(Bs[buf] + srow * LDK + shf * 16)     = pb0;
        *(uint4*)(Bs[buf] + srow * LDK + shf * 16 + 8) = pb1;
    };

    issue(0);
    commit(0, 0);
    __syncthreads();

    for (int kc = 0; kc < 9; kc++) {
        const int cur = kc & 1;
        if (kc < 8) issue(kc + 1);            // loads in flight over MFMAs

        v8h af[2], bf[8];
        #pragma unroll
        for (int mi = 0; mi < 2; mi++)
            af[mi] = *(const v8h*)(As[cur] + (wv * 32 + mi * 16 + r15) * LDK + q * 8);
        #pragma unroll
        for (int nj = 0; nj < 8; nj++)
            bf[nj] = *(const v8h*)(Bs[cur] + (nj * 16 + r15) * LDK + q * 8);
        #pragma unroll
        for (int mi = 0; mi < 2; mi++)
            #pragma unroll
            for (int nj = 0; nj < 8; nj++)
                acc[mi][nj] = __builtin_amdgcn_mfma_f32_16x16x32_f16(
                    af[mi], bf[nj], acc[mi][nj], 0, 0, 0);

        if (kc < 8) {
            commit(cur ^ 1, kc + 1);          // drain vmcnt here, not earlier
            __syncthreads();                  // single barrier per kc
        }
    }

    #pragma unroll
    for (int mi = 0; mi < 2; mi++) {
        #pragma unroll
        for (int nj = 0; nj < 8; nj++) {
            int col = gt * 128 + nj * 16 + r15;
            float bv = bias[col];
            #pragma unroll
            for (int v = 0; v < 4; v++) {
                int row = mt * 128 + wv * 32 + mi * 16 + q * 4 + v;
                float val = acc[mi][nj][v] + bv;
                gxa[row * GG + col] = f2h(val);
            }
        }
    }
}

// ---------------------------------------------------------------------------
// Kernel 3: MFMA-batched GRU scan (unchanged from previous round).
// ---------------------------------------------------------------------------
__global__ __launch_bounds__(512, 2) void scan_mfma(
    const unsigned short* __restrict__ gxa, const uint4* __restrict__ whb4,
    const unsigned char* __restrict__ rst, const int* __restrict__ Ftab,
    const float* __restrict__ ihg, float* __restrict__ out)
{
    __shared__ __align__(16) unsigned short h16[SGRP * LDH];
    __shared__ __align__(16) unsigned short rh16[SGRP * LDH];
    __shared__ __align__(16) unsigned short gstage[2][SGRP * GSP];
    __shared__ __align__(16) uint4 waL[8 * 8 * 64];   // aa1 tiles [w][kt][lane]
    __shared__ int s_tb[SGRP], s_te[SGRP], s_emax;

    const int tid = threadIdx.x;
    const int w = tid >> 6, lane = tid & 63;
    const int r15 = lane & 15, q = lane >> 4;
    const int grp = blockIdx.x >> 6;        // 0..3
    const int c   = blockIdx.x & (NCH - 1); // 0..63
    const int n0  = grp * SGRP;
    const int S   = c * WCH;

    // ---- weights: 40 reg fragments + 8 LDS fragments per wave ----
    uint4 wb[40];
    #pragma unroll
    for (int i = 0; i < 40; i++) wb[i] = whb4[(w * 48 + i) * 64 + lane];
    #pragma unroll
    for (int rr = 0; rr < 8; rr++) {
        int f = rr * 512 + tid;             // [w=rr][kt=tid>>6][lane=tid&63]
        waL[f] = whb4[(rr * 48 + 40 + (tid >> 6)) * 64 + (tid & 63)];
    }

    if (tid < SGRP) {
        s_tb[tid] = (c == 0) ? 0 : Ftab[(n0 + tid) * (NCH + 1) + c];
        s_te[tid] = Ftab[(n0 + tid) * (NCH + 1) + c + 1];
    }
    if (tid == 0) {   // same wave as tid<16 writers: in-wave LDS ordering
        int m = 0;
        for (int i = 0; i < SGRP; i++) m = max(m, s_te[i]);
        s_emax = m;
    }
    // init h16: (c==0 || reset at S) ? ih : 0  (pre-tb values are masked)
    for (int idx = tid; idx < SGRP * HH; idx += 512) {
        int sq = idx >> 8, jj = idx & 255;
        bool rb = (c == 0) || (rst[(n0 + sq) * TT + S] != 0);
        float v = rb ? ihg[jj] : 0.f;
        h16[sq * LDH + jj] = f2h(v);
    }
    // initial gxa stage for t = S
    const int seqS = tid >> 5, jS = tid & 31;
    {
        const uint4* sp = (const uint4*)(gxa + ((size_t)(n0 + seqS) * TT + S) * GG);
        uint4 g0 = sp[jS], g1 = sp[jS + 32], g2 = sp[jS + 64];
        uint4* dp = (uint4*)(gstage[0] + seqS * GSP);
        dp[jS] = g0; dp[jS + 32] = g1; dp[jS + 64] = g2;
    }
    __syncthreads();
    const int Emax = s_emax;

    const int j0 = w * 32 + r15, j1 = j0 + 16;
    const float ih0 = ihg[j0], ih1 = ihg[j1];

    int   seqi[4];    // (n0+seq)*TT row bases for this lane's 4 C-rows
    int   tbte[4];    // tb | te<<16
    float hcr[8];     // fp32 h owned by this lane
    #pragma unroll
    for (int v = 0; v < 4; v++) {
        int sq = q * 4 + v;
        seqi[v] = (n0 + sq) * TT;
        tbte[v] = s_tb[sq] | (s_te[sq] << 16);
        bool rb = (c == 0) || (rst[seqi[v] + S] != 0);
        hcr[v]     = rb ? ih0 : 0.f;
        hcr[4 + v] = rb ? ih1 : 0.f;
    }

    const v4f z4 = {0.f, 0.f, 0.f, 0.f};

    for (int t = S; t < Emax; t++) {
        const int cur = (t - S) & 1, nxt = cur ^ 1;
        const int tn = (t + 1 < TT) ? (t + 1) : (TT - 1);

        // ---- issue next-step global loads (drain at step bottom) ----
        uint4 g0, g1, g2;
        {
            const uint4* sp = (const uint4*)(gxa + ((size_t)(n0 + seqS) * TT + tn) * GG);
            g0 = sp[jS]; g1 = sp[jS + 32]; g2 = sp[jS + 64];
        }
        unsigned char rn[4];
        #pragma unroll
        for (int v = 0; v < 4; v++) rn[v] = rst[seqi[v] + tn];

        // ---- phase 1: zr = h @ Wzr  (32 MFMAs/wave) ----
        v4f az0 = z4, az1 = z4, ar0 = z4, ar1 = z4;
        #pragma unroll
        for (int kt = 0; kt < 8; kt++) {
            v8h af = *(const v8h*)(h16 + r15 * LDH + kt * 32 + q * 8);
            az0 = __builtin_amdgcn_mfma_f32_16x16x32_f16(af, __builtin_bit_cast(v8h, wb[kt]),      az0, 0, 0, 0);
            az1 = __builtin_amdgcn_mfma_f32_16x16x32_f16(af, __builtin_bit_cast(v8h, wb[8 + kt]),  az1, 0, 0, 0);
            ar0 = __builtin_amdgcn_mfma_f32_16x16x32_f16(af, __builtin_bit_cast(v8h, wb[16 + kt]), ar0, 0, 0, 0);
            ar1 = __builtin_amdgcn_mfma_f32_16x16x32_f16(af, __builtin_bit_cast(v8h, wb[24 + kt]), ar1, 0, 0, 0);
        }

        // ---- epilogue 1: sigmoid; z kept local; rh -> LDS (fp16) ----
        const unsigned short* gs = gstage[cur];
        float zs[8];
        #pragma unroll
        for (int v = 0; v < 4; v++) {
            int sq = q * 4 + v;
            int gb = sq * GSP;
            float z0 = az0[v] + h2f(gs[gb + j0]);
            float z1 = az1[v] + h2f(gs[gb + j1]);
            zs[v]     = 1.f / (1.f + __expf(-z0));
            zs[4 + v] = 1.f / (1.f + __expf(-z1));
            float r0 = ar0[v] + h2f(gs[gb + 256 + j0]);
            float r1 = ar1[v] + h2f(gs[gb + 256 + j1]);
            float s0 = 1.f / (1.f + __expf(-r0));
            float s1 = 1.f / (1.f + __expf(-r1));
            rh16[sq * LDH + j0] = f2h(s0 * hcr[v]);
            rh16[sq * LDH + j1] = f2h(s1 * hcr[4 + v]);
        }
        __syncthreads();   // B1: rh16 ready

        // ---- phase 2: a = rh @ Wa  (16 MFMAs/wave, 8 B-frags from LDS) ----
        v4f aa0 = z4, aa1 = z4;
        #pragma unroll
        for (int kt = 0; kt < 8; kt++) {
            v8h af = *(const v8h*)(rh16 + r15 * LDH + kt * 32 + q * 8);
            uint4 wv4 = waL[(w * 8 + kt) * 64 + lane];
            aa0 = __builtin_amdgcn_mfma_f32_16x16x32_f16(af, __builtin_bit_cast(v8h, wb[32 + kt]), aa0, 0, 0, 0);
            aa1 = __builtin_amdgcn_mfma_f32_16x16x32_f16(af, __builtin_bit_cast(v8h, wv4),         aa1, 0, 0, 0);
        }

        // ---- epilogue 2: tanh, state update, masked store, next reset ----
        #pragma unroll
        for (int v = 0; v < 4; v++) {
            int sq = q * 4 + v;
            int gb = sq * GSP;
            int tb = tbte[v] & 0xFFFF, te = tbte[v] >> 16;
            bool wr = (t >= tb) && (t < te);
            int mo = (seqi[v] + t) * HH;
            float u0 = aa0[v] + h2f(gs[gb + 512 + j0]);
            float u1 = aa1[v] + h2f(gs[gb + 512 + j1]);
            float e0 = __expf(2.f * u0), e1 = __expf(2.f * u1);
            float t0 = (e0 - 1.f) / (e0 + 1.f);
            float t1 = (e1 - 1.f) / (e1 + 1.f);
            float hn0 = hcr[v]     + zs[v]     * (t0 - hcr[v]);
            float hn1 = hcr[4 + v] + zs[4 + v] * (t1 - hcr[4 + v]);
            if (wr) {
                out[mo + j0] = hn0;
                out[mo + j1] = hn1;
                out[MM * HH + mo + j0] = hn0;
                out[MM * HH + mo + j1] = hn1;
            }
            bool rb = rn[v] != 0;
            float g0f = rb ? ih0 : hn0;
            float g1f = rb ? ih1 : hn1;
            hcr[v] = g0f; hcr[4 + v] = g1f;
            h16[sq * LDH + j0] = f2h(g0f);
            h16[sq * LDH + j1] = f2h(g1f);
        }

        // ---- write staged gxa for t+1 (loads drained here, not earlier) ----
        {
            uint4* dp = (uint4*)(gstage[nxt] + seqS * GSP);
            dp[jS] = g0; dp[jS + 32] = g1; dp[jS + 64] = g2;
        }
        __syncthreads();   // B2: h16 + gstage[nxt] ready for next step
    }
}

// ---------------------------------------------------------------------------
extern "C" void kernel_launch(void* const* d_in, const int* in_sizes, int n_in,
                              void* d_out, int out_size, void* d_ws, size_t ws_size,
                              hipStream_t stream)
{
    const float* x   = (const float*)d_in[0];
    const float* a   = (const float*)d_in[1];
    const void*  rsv = d_in[2];
    const float* w_i = (const float*)d_in[3];
    const float* w_h = (const float*)d_in[4];
    const float* w_a = (const float*)d_in[5];
    const float* b   = (const float*)d_in[6];
    const float* ih  = (const float*)d_in[7];
    float*       out = (float*)d_out;

    char* ws = (char*)d_ws;
    size_t o = 0;
    unsigned short* gxa  = (unsigned short*)(ws + o); o += (size_t)MM * GG * 2;  // 96 MB
    unsigned short* wt   = (unsigned short*)(ws + o); o += (size_t)GG * KP * 2;  // 0.44 MB
    unsigned char*  rst8 = (unsigned char*) (ws + o); o += (size_t)NB * TT;      // 64 KB
    unsigned*       whb  = (unsigned*)      (ws + o); o += 98304u * 4;           // 384 KB
    int*            Ftab = (int*)           (ws + o);                            // 16.6 KB

    fix_reset<<<1, 1024, 0, stream>>>((const unsigned*)rsv, rst8, Ftab);

    prep_weights<<<865 + 384, 256, 0, stream>>>(
        w_i, w_a, w_h, ih, out + (size_t)2 * MM * HH, wt, whb);

    gemm_fused<<<512 * 6, 256, 0, stream>>>(x, a, wt, b, gxa);

    scan_mfma<<<(NB / SGRP) * NCH, 512, 0, stream>>>(
        gxa, (const uint4*)whb, rst8, Ftab, ih, out);
}